// Round 1
// baseline (102.549 us; speedup 1.0000x reference)
//
#include <hip/hip_runtime.h>
#include <cmath>

// MXIntGELU: mxint8 (block=32, e4) quantize -> exact-erf GELU hashed to 8b/5fb
// with exponent-aligned floor requant -> mxint8 output quantize.
// Blocks are 32 CONTIGUOUS floats (p1=1, p0=32, t0=4096 % 32 == 0).
// One thread = 4 consecutive floats (float4); 8 lanes = one 32-elem block.

__device__ __forceinline__ float pow2i(int k) {
    // exact 2^k for k in [-126, 127]
    union { unsigned u; float f; } c;
    c.u = (unsigned)(127 + k) << 23;
    return c.f;
}

__device__ __forceinline__ int block_exp(float amax) {
    // clip(floor(log2(max(amax, 2^-8))), -8, 7) -- exact floor(log2) via ilogb
    int e = ilogbf(fmaxf(amax, 0x1p-8f));
    return max(-8, min(7, e));
}

__global__ __launch_bounds__(256) void mxint_gelu_kernel(
    const float* __restrict__ in, float* __restrict__ out, unsigned n4)
{
    unsigned i = blockIdx.x * 256u + threadIdx.x;
    if (i >= n4) return;

    const float4 xv = reinterpret_cast<const float4*>(in)[i];
    float x[4] = {xv.x, xv.y, xv.z, xv.w};

    // ---- input block amax over 32 elems (8 lanes x 4) ----
    float amax = fmaxf(fmaxf(fabsf(x[0]), fabsf(x[1])),
                       fmaxf(fabsf(x[2]), fabsf(x[3])));
    amax = fmaxf(amax, __shfl_xor(amax, 1, 64));
    amax = fmaxf(amax, __shfl_xor(amax, 2, 64));
    amax = fmaxf(amax, __shfl_xor(amax, 4, 64));

    const int ex1 = block_exp(amax);
    const float s1  = pow2i(7 - ex1);   // 128 / 2^ex1
    const float is1 = pow2i(ex1 - 7);   // 2^ex1 / 128

    float o[4];
    float oamax = 0.f;
    #pragma unroll
    for (int j = 0; j < 4; ++j) {
        // mxint quantize input: round-half-even, clip [-128,127], dequant
        float m = rintf(x[j] * s1);
        m = fminf(fmaxf(m, -128.f), 127.f);
        const float q = m * is1;

        float r = fmaxf(q, 0.f);                 // relu path
        if (q > -3.f && q < 3.f) {
            // exact GELU: q * (erf(q/sqrt(2)) + 1) / 2, erf in f64 for
            // correctly-rounded f32 result (t itself is ref's f32 division)
            const float t = q / 1.41421356237309504880f;
            const float e = (float)erf((double)t);
            const float g = q * (e + 1.f) * 0.5f;
            // hash output quantize: 8 bits, 5 frac bits
            float qg = rintf(g * 32.f);
            qg = fminf(fmaxf(qg, -128.f), 127.f);
            const float qgelu = qg * 0.03125f;
            // exponent-aligned floor requant
            const float mg = floorf(qgelu * s1);
            r = mg * is1;
        }
        o[j] = r;
        oamax = fmaxf(oamax, fabsf(r));
    }

    // ---- output block amax ----
    oamax = fmaxf(oamax, __shfl_xor(oamax, 1, 64));
    oamax = fmaxf(oamax, __shfl_xor(oamax, 2, 64));
    oamax = fmaxf(oamax, __shfl_xor(oamax, 4, 64));

    const int ex2 = block_exp(oamax);
    const float s2  = pow2i(7 - ex2);
    const float is2 = pow2i(ex2 - 7);

    float4 yv;
    float y[4];
    #pragma unroll
    for (int j = 0; j < 4; ++j) {
        float m = rintf(o[j] * s2);
        m = fminf(fmaxf(m, -128.f), 127.f);
        y[j] = m * is2;
    }
    yv.x = y[0]; yv.y = y[1]; yv.z = y[2]; yv.w = y[3];
    reinterpret_cast<float4*>(out)[i] = yv;
}

extern "C" void kernel_launch(void* const* d_in, const int* in_sizes, int n_in,
                              void* d_out, int out_size, void* d_ws, size_t ws_size,
                              hipStream_t stream) {
    const float* x = (const float*)d_in[0];
    float* y = (float*)d_out;
    const unsigned n = (unsigned)in_sizes[0];   // 33,554,432 (divisible by 128)
    const unsigned n4 = n / 4;
    const unsigned blocks = (n4 + 255u) / 256u;
    mxint_gelu_kernel<<<blocks, 256, 0, stream>>>(x, y, n4);
}

// Round 2
// 50.929 us; speedup vs baseline: 2.0136x; 2.0136x over previous
//
#include <hip/hip_runtime.h>
#include <cmath>

// MXIntGELU via 4096-entry LUT: the inner transform (mxint8 dequant -> exact-erf
// GELU quantized to 8b/5fb -> exponent-aligned floor requant / relu) is a pure
// function of (block_exponent ex1 in [-8,7], mantissa m in [-128,127]).
// Build the LUT once with f64 erf (bit-identical to the direct computation),
// then the main kernel is a memory-bound streaming pass with one LDS gather
// per element.

__device__ __forceinline__ float pow2i(int k) {
    // exact 2^k for k in [-126, 127]
    union { unsigned u; float f; } c;
    c.u = (unsigned)(127 + k) << 23;
    return c.f;
}

__device__ __forceinline__ int block_exp(float amax) {
    // clip(floor(log2(max(amax, 2^-8))), -8, 7) -- exact floor(log2) via ilogb
    int e = ilogbf(fmaxf(amax, 0x1p-8f));
    return max(-8, min(7, e));
}

__global__ __launch_bounds__(256) void build_lut_kernel(float* __restrict__ lut) {
    const int idx = blockIdx.x * 256 + threadIdx.x;   // 0..4095
    const int e = (idx >> 8) - 8;
    const int m = (idx & 255) - 128;
    const float q = (float)m * pow2i(e - 7);
    float r = fmaxf(q, 0.f);                          // relu path
    if (q > -3.f && q < 3.f) {
        const float t = q / 1.41421356237309504880f;
        const float er = (float)erf((double)t);       // correctly-rounded f32 erf
        const float g = q * (er + 1.f) * 0.5f;
        float qg = rintf(g * 32.f);                   // 8b / 5 frac-bit hash quant
        qg = fminf(fmaxf(qg, -128.f), 127.f);
        const float qgelu = qg * 0.03125f;
        const float mg = floorf(qgelu * pow2i(7 - e)); // exponent-aligned floor
        r = mg * pow2i(e - 7);
    }
    lut[idx] = r;
}

__global__ __launch_bounds__(256) void mxint_gelu_lut_kernel(
    const float* __restrict__ in, float* __restrict__ out,
    const float* __restrict__ glut, unsigned n8)
{
    __shared__ float lut[4096];
    {   // fill LDS LUT: 256 threads x 4 x float4 (coalesced, conflict-free)
        const float4* g4 = reinterpret_cast<const float4*>(glut);
        float4* l4 = reinterpret_cast<float4*>(lut);
        #pragma unroll
        for (int k = 0; k < 4; ++k)
            l4[threadIdx.x + 256 * k] = g4[threadIdx.x + 256 * k];
    }
    __syncthreads();

    const unsigned stride = gridDim.x * 256u;
    for (unsigned u = blockIdx.x * 256u + threadIdx.x; u < n8; u += stride) {
        // thread owns 8 consecutive floats; a lane-quad owns one 32-block
        const float4* p = reinterpret_cast<const float4*>(in) + 2 * (size_t)u;
        const float4 va = p[0], vb = p[1];
        float x[8] = {va.x, va.y, va.z, va.w, vb.x, vb.y, vb.z, vb.w};

        float amax = 0.f;
        #pragma unroll
        for (int j = 0; j < 8; ++j) amax = fmaxf(amax, fabsf(x[j]));
        amax = fmaxf(amax, __shfl_xor(amax, 1, 64));
        amax = fmaxf(amax, __shfl_xor(amax, 2, 64));

        const int ex1 = block_exp(amax);
        const float s1 = pow2i(7 - ex1);          // 128 / 2^ex1
        const int base = (ex1 + 8) * 256 + 128;

        float o[8];
        float oamax = 0.f;
        #pragma unroll
        for (int j = 0; j < 8; ++j) {
            float m = rintf(x[j] * s1);           // round-half-even
            m = fminf(fmaxf(m, -128.f), 127.f);
            const float r = lut[base + (int)m];
            o[j] = r;
            oamax = fmaxf(oamax, fabsf(r));
        }

        oamax = fmaxf(oamax, __shfl_xor(oamax, 1, 64));
        oamax = fmaxf(oamax, __shfl_xor(oamax, 2, 64));
        const int ex2 = block_exp(oamax);
        const float s2 = pow2i(7 - ex2);
        const float is2 = pow2i(ex2 - 7);

        float y[8];
        #pragma unroll
        for (int j = 0; j < 8; ++j) {
            float m = rintf(o[j] * s2);
            m = fminf(fmaxf(m, -128.f), 127.f);
            y[j] = m * is2;
        }
        float4* q = reinterpret_cast<float4*>(out) + 2 * (size_t)u;
        q[0] = make_float4(y[0], y[1], y[2], y[3]);
        q[1] = make_float4(y[4], y[5], y[6], y[7]);
    }
}

// Fallback (ws too small): direct computation, identical numerics.
__global__ __launch_bounds__(256) void mxint_gelu_direct_kernel(
    const float* __restrict__ in, float* __restrict__ out, unsigned n4)
{
    unsigned i = blockIdx.x * 256u + threadIdx.x;
    if (i >= n4) return;
    const float4 xv = reinterpret_cast<const float4*>(in)[i];
    float x[4] = {xv.x, xv.y, xv.z, xv.w};
    float amax = fmaxf(fmaxf(fabsf(x[0]), fabsf(x[1])),
                       fmaxf(fabsf(x[2]), fabsf(x[3])));
    amax = fmaxf(amax, __shfl_xor(amax, 1, 64));
    amax = fmaxf(amax, __shfl_xor(amax, 2, 64));
    amax = fmaxf(amax, __shfl_xor(amax, 4, 64));
    const int ex1 = block_exp(amax);
    const float s1 = pow2i(7 - ex1), is1 = pow2i(ex1 - 7);
    float o[4]; float oamax = 0.f;
    #pragma unroll
    for (int j = 0; j < 4; ++j) {
        float m = rintf(x[j] * s1);
        m = fminf(fmaxf(m, -128.f), 127.f);
        const float q = m * is1;
        float r = fmaxf(q, 0.f);
        if (q > -3.f && q < 3.f) {
            const float t = q / 1.41421356237309504880f;
            const float e = (float)erf((double)t);
            const float g = q * (e + 1.f) * 0.5f;
            float qg = rintf(g * 32.f);
            qg = fminf(fmaxf(qg, -128.f), 127.f);
            const float mg = floorf(qg * 0.03125f * s1);
            r = mg * is1;
        }
        o[j] = r; oamax = fmaxf(oamax, fabsf(r));
    }
    oamax = fmaxf(oamax, __shfl_xor(oamax, 1, 64));
    oamax = fmaxf(oamax, __shfl_xor(oamax, 2, 64));
    oamax = fmaxf(oamax, __shfl_xor(oamax, 4, 64));
    const int ex2 = block_exp(oamax);
    const float s2 = pow2i(7 - ex2), is2 = pow2i(ex2 - 7);
    float y[4];
    #pragma unroll
    for (int j = 0; j < 4; ++j) {
        float m = rintf(o[j] * s2);
        m = fminf(fmaxf(m, -128.f), 127.f);
        y[j] = m * is2;
    }
    reinterpret_cast<float4*>(out)[i] =
        make_float4(y[0], y[1], y[2], y[3]);
}

extern "C" void kernel_launch(void* const* d_in, const int* in_sizes, int n_in,
                              void* d_out, int out_size, void* d_ws, size_t ws_size,
                              hipStream_t stream) {
    const float* x = (const float*)d_in[0];
    float* y = (float*)d_out;
    const unsigned n = (unsigned)in_sizes[0];   // 33,554,432

    if (ws_size >= 4096 * sizeof(float) && (n % 8u) == 0u) {
        float* lut = (float*)d_ws;
        build_lut_kernel<<<16, 256, 0, stream>>>(lut);
        const unsigned n8 = n / 8;
        unsigned blocks = 2048;                 // 8 blocks/CU, grid-stride
        if (blocks * 256u > n8) blocks = (n8 + 255u) / 256u;
        mxint_gelu_lut_kernel<<<blocks, 256, 0, stream>>>(x, y, lut, n8);
    } else {
        const unsigned n4 = n / 4;
        mxint_gelu_direct_kernel<<<(n4 + 255u) / 256u, 256, 0, stream>>>(x, y, n4);
    }
}